// Round 6
// baseline (102.148 us; speedup 1.0000x reference)
//
#include <hip/hip_runtime.h>
#include <hip/hip_bf16.h>

#define THRESH 0.05f
constexpr int B_   = 32;
constexpr int CIN  = 128;
constexpr int COUT = 256;
constexpr int HH   = 56;
constexpr int WW   = 56;
constexpr int HWSZ = HH * WW;            // 3136
constexpr int WELEM = COUT * CIN * 9;    // 294912
constexpr int PADW = 58;                 // padded spatial dim

typedef unsigned short u16;
typedef __attribute__((ext_vector_type(4))) float  f32x4;
typedef __attribute__((ext_vector_type(8))) short  s16x8;

typedef const __attribute__((address_space(1))) void* gas1;
typedef __attribute__((address_space(3))) void* las3;
#define GLOAD16(gsrc, ldst) \
    __builtin_amdgcn_global_load_lds((gas1)(gsrc), (las3)(ldst), 16, 0, 0)

static __device__ __forceinline__ u16 f2bf(float f) {
    __hip_bfloat16 h = __float2bfloat16(f);
    return *reinterpret_cast<u16*>(&h);
}

// ---------------------------------------------------------------------------
// Kernel 1: per-block maxabs partials
// ---------------------------------------------------------------------------
__global__ __launch_bounds__(256) void maxabs_part(const float* __restrict__ w,
                                                   float* __restrict__ partial) {
    int tid = threadIdx.x;
    float m = 0.0f;
    for (int i = blockIdx.x * 256 + tid; i < WELEM; i += 256 * 256)
        m = fmaxf(m, fabsf(w[i]));
    #pragma unroll
    for (int off = 32; off > 0; off >>= 1) m = fmaxf(m, __shfl_xor(m, off));
    __shared__ float s[4];
    if ((tid & 63) == 0) s[tid >> 6] = m;
    __syncthreads();
    if (tid == 0) partial[blockIdx.x] = fmaxf(fmaxf(s[0], s[1]), fmaxf(s[2], s[3]));
}

// ---------------------------------------------------------------------------
// Kernel 2: reduce + faithful ternary quantize + pack bf16 into PERMUTED layout
// Apack u16 index: ((cc*4 + cot)*64 + row)*288 + tap*32 + (g ^ ((row>>1)&3))*8 + e
// ---------------------------------------------------------------------------
__global__ __launch_bounds__(256) void quant_pack(const float* __restrict__ w,
                                                  const float* __restrict__ partial,
                                                  const float* __restrict__ Wn,
                                                  u16* __restrict__ Apack) {
    int tid = threadIdx.x;
    float m = partial[tid];
    #pragma unroll
    for (int off = 32; off > 0; off >>= 1) m = fmaxf(m, __shfl_xor(m, off));
    __shared__ float s[4];
    if ((tid & 63) == 0) s[tid >> 6] = m;
    __syncthreads();
    const float mx = fmaxf(fmaxf(s[0], s[1]), fmaxf(s[2], s[3]));
    const float wn = Wn[0];

    int idx = blockIdx.x * 256 + tid;          // ((co*128+ci)*9+tap)
    float nw = w[idx] / mx;
    float q  = (nw > -THRESH && nw <= THRESH) ? 0.0f : nw;
    if (q >  THRESH) q =  1.0f;
    if (q < -THRESH) q = -1.0f;
    if (q == -1.0f)  q = wn;

    int tap = idx % 9;
    int r   = idx / 9;
    int ci  = r % CIN;
    int co  = r / CIN;
    int cc  = ci >> 5, lci = ci & 31, g = lci >> 3, e = lci & 7;
    int cot = co >> 6, row = co & 63;
    int swz = g ^ ((row >> 1) & 3);
    Apack[(size_t)((cc * 4 + cot) * 64 + row) * 288 + tap * 32 + swz * 8 + e] = f2bf(q);
}

// ---------------------------------------------------------------------------
// Kernel 3: zero the borders of padded Xt
// ---------------------------------------------------------------------------
__global__ __launch_bounds__(256) void xpad_zero(u16* __restrict__ XtP) {
    const int n = blockIdx.x;
    for (int idx = threadIdx.x; idx < 3648; idx += 256) {
        int c16 = idx & 15, s = idx >> 4;
        int r, c;
        if      (s < 58)  { r = 0;           c = s; }
        else if (s < 116) { r = 57;          c = s - 58; }
        else if (s < 172) { r = s - 116 + 1; c = 0; }
        else              { r = s - 172 + 1; c = 57; }
        size_t site = (size_t)(n * PADW + r) * PADW + c;
        *(s16x8*)(XtP + site * 128 + c16 * 8) = (s16x8){0,0,0,0,0,0,0,0};
    }
}

// ---------------------------------------------------------------------------
// Kernel 4: X (NCHW f32) -> padded Xt[n][1+h][1+w][ci] bf16 via LDS transpose
// ---------------------------------------------------------------------------
__global__ __launch_bounds__(256) void x_to_bf16t(const float* __restrict__ X,
                                                  u16* __restrict__ XtP) {
    __shared__ u16 T[64 * 136];
    const int b  = blockIdx.x;
    const int n  = b / 49, pt = b - n * 49;
    const int p0 = pt * 64;
    const int tid = threadIdx.x;
    const int ci  = tid >> 1, h2 = tid & 1;

    const float* src = X + ((size_t)(n * CIN + ci)) * HWSZ + p0 + h2 * 32;
    #pragma unroll
    for (int j = 0; j < 8; ++j) {
        f32x4 v = *(const f32x4*)(src + j * 4);
        #pragma unroll
        for (int mth = 0; mth < 4; ++mth)
            T[(h2 * 32 + j * 4 + mth) * 136 + ci] = f2bf(v[mth]);
    }
    __syncthreads();
    #pragma unroll
    for (int k = 0; k < 4; ++k) {
        int idx = tid + k * 256;
        int p = idx >> 4, c8 = idx & 15;
        int gp = p0 + p;
        int h = gp / 56, w = gp - h * 56;
        size_t site = (size_t)(n * PADW + 1 + h) * PADW + 1 + w;
        *(s16x8*)(XtP + site * 128 + c8 * 8) = *(const s16x8*)&T[p * 136 + c8 * 8];
    }
}

// ---------------------------------------------------------------------------
// Kernel 5: implicit-GEMM conv — SINGLE-buffered 2-phase, 2 blocks/CU.
// 512 thr / 8 waves, tile 64 co x 8 rows. LDS = 36.9 + 41 = 77.8 KB so TWO
// blocks co-reside per CU (16 waves/CU): one block's stage+drain overlaps the
// other block's 9-tap MFMA stream (m97/m114 mechanism). Per cc-chunk:
// {stage A+B -> vmcnt(0)+barrier -> 9 taps (no inner barriers, compiler
// lgkmcnt-pipelined, setprio-wrapped) -> barrier}.
// ---------------------------------------------------------------------------
__global__ __launch_bounds__(512, 4) void conv_mfma(const u16* __restrict__ XtP,
                                                    const u16* __restrict__ Apack,
                                                    float* __restrict__ out) {
    __shared__ u16 Alds[18432];     // 36,864 B : [64 row][288 k] linear
    __shared__ u16 Xlds[20480];     // 40,960 B : [640 site][32 ci] linear

    const int tid  = threadIdx.x;
    const int wid  = tid >> 6;
    const int lane = tid & 63;
    const int r16  = lane & 15;
    const int g    = lane >> 4;

    // XCD swizzle: 896 blocks, 112 per XCD -> XCD x owns images 4x..4x+3
    const int bid = blockIdx.x;
    const int s   = (bid & 7) * 112 + (bid >> 3);
    const int n   = s / 28;
    const int rem = s - n * 28;
    const int by  = rem >> 2;
    const int bx  = rem & 3;
    const int co0 = bx * 64;
    const int h0  = by * 8;

    f32x4 acc[4][4];
    #pragma unroll
    for (int i = 0; i < 4; ++i)
        #pragma unroll
        for (int j = 0; j < 4; ++j) acc[i][j] = (f32x4){0.f, 0.f, 0.f, 0.f};

    // ---- B-staging source offsets (u16 units, sans cc term) ----
    const int hbase = n * PADW + h0;
    unsigned int bsrc[5];
    #pragma unroll
    for (int i = 0; i < 5; ++i) {
        int p  = i * 512 + tid;
        int pc = (p < 2320) ? p : (p - 2320);       // clamp tail to valid sites
        int site = pc >> 2, gg = pc & 3;
        int r = site / 58, c = site - r * 58;
        int g2 = gg ^ ((site >> 1) & 3);
        bsrc[i] = (unsigned)(((hbase + r) * PADW + c) * 128 + g2 * 8);
    }

    // ---- A fragment base (u16 units): XOR term invariant in mf & tap ----
    const int abase0 = r16 * 288 + ((g ^ ((r16 >> 1) & 3)) << 3);

    // ---- B per-tap offsets (u16 units): XOR term invariant in nf ----
    int otap[9];
    #pragma unroll
    for (int t = 0; t < 9; ++t) {
        int base_t = (wid + t / 3) * 58 + r16 + (t % 3);
        otap[t] = base_t * 32 + ((g ^ ((base_t >> 1) & 3)) << 3);
    }

    #pragma unroll
    for (int cc = 0; cc < 4; ++cc) {
        // ---- stage chunk cc into the single buffer ----
        const u16* asrc = Apack + (size_t)(cc * 4 + bx) * 18432;
        #pragma unroll
        for (int i = 0; i < 4; ++i)
            GLOAD16(asrc + (size_t)(i * 512 + tid) * 8, &Alds[(i * 512 + wid * 64) * 8]);
        if (wid < 4)
            GLOAD16(asrc + (size_t)(2048 + wid * 64 + lane) * 8, &Alds[(2048 + wid * 64) * 8]);
        #pragma unroll
        for (int i = 0; i < 5; ++i)
            GLOAD16(XtP + (size_t)bsrc[i] + cc * 32, &Xlds[(i * 512 + wid * 64) * 8]);

        asm volatile("s_waitcnt vmcnt(0)" ::: "memory");
        __builtin_amdgcn_s_barrier();
        __builtin_amdgcn_sched_barrier(0);

        // ---- 9-tap MFMA stream, no inner barriers ----
        const u16* Ab = &Alds[abase0];
        const u16* Xb = &Xlds[0];
        __builtin_amdgcn_s_setprio(1);
        #pragma unroll
        for (int t = 0; t < 9; ++t) {
            s16x8 af[4], bfr[4];
            #pragma unroll
            for (int mf = 0; mf < 4; ++mf)
                af[mf] = *(const s16x8*)(Ab + mf * 4608 + t * 32);
            #pragma unroll
            for (int nf = 0; nf < 4; ++nf)
                bfr[nf] = *(const s16x8*)(Xb + otap[t] + nf * 512);
            #pragma unroll
            for (int mf = 0; mf < 4; ++mf)
                #pragma unroll
                for (int nf = 0; nf < 4; ++nf)
                    acc[mf][nf] = __builtin_amdgcn_mfma_f32_16x16x32_bf16(
                        af[mf], bfr[nf], acc[mf][nf], 0, 0, 0);
        }
        __builtin_amdgcn_s_setprio(0);
        __builtin_amdgcn_sched_barrier(0);

        // ---- protect buffer before next chunk's stage overwrites ----
        if (cc < 3)
            __builtin_amdgcn_s_barrier();
    }

    // ---- store: D col = r16 (spatial), row = g*4+j (co) ----
    const int h = h0 + wid;
    float* obase = out + ((size_t)(n * COUT + co0)) * HWSZ + h * WW;
    #pragma unroll
    for (int mf = 0; mf < 4; ++mf)
        #pragma unroll
        for (int nf = 0; nf < 4; ++nf) {
            int col = nf * 16 + r16;
            if (col < WW) {
                #pragma unroll
                for (int j = 0; j < 4; ++j) {
                    int co = mf * 16 + g * 4 + j;
                    obase[(size_t)co * HWSZ + col] = acc[mf][nf][j];
                }
            }
        }
}

// ---------------------------------------------------------------------------
// Launch
// ---------------------------------------------------------------------------
extern "C" void kernel_launch(void* const* d_in, const int* in_sizes, int n_in,
                              void* d_out, int out_size, void* d_ws, size_t ws_size,
                              hipStream_t stream) {
    const float* X      = (const float*)d_in[0];
    const float* weight = (const float*)d_in[1];
    // Wp (d_in[2]) never enters the forward (faithful to source)
    const float* Wn     = (const float*)d_in[3];
    float* out = (float*)d_out;

    float* ws_partial = (float*)d_ws;                        // 256 f32
    u16*   ws_apack   = (u16*)((char*)d_ws + 4096);          // 294912 u16
    u16*   ws_xtp     = (u16*)((char*)d_ws + (1 << 20));     // 32*3364*128 u16 (~27.5 MB)

    maxabs_part<<<256, 256, 0, stream>>>(weight, ws_partial);
    quant_pack<<<WELEM / 256, 256, 0, stream>>>(weight, ws_partial, Wn, ws_apack);
    xpad_zero<<<B_, 256, 0, stream>>>(ws_xtp);
    x_to_bf16t<<<B_ * (HWSZ / 64), 256, 0, stream>>>(X, ws_xtp);

    conv_mfma<<<896, 512, 0, stream>>>(ws_xtp, ws_apack, out);
}

// Round 7
// 94.490 us; speedup vs baseline: 1.0810x; 1.0810x over previous
//
#include <hip/hip_runtime.h>
#include <hip/hip_bf16.h>

#define THRESH 0.05f
constexpr int B_   = 32;
constexpr int CIN  = 128;
constexpr int COUT = 256;
constexpr int HH   = 56;
constexpr int WW   = 56;
constexpr int HWSZ = HH * WW;            // 3136
constexpr int WELEM = COUT * CIN * 9;    // 294912
constexpr int PADW = 58;                 // padded spatial dim

typedef unsigned short u16;
typedef __attribute__((ext_vector_type(4))) float  f32x4;
typedef __attribute__((ext_vector_type(8))) short  s16x8;

typedef const __attribute__((address_space(1))) void* gas1;
typedef __attribute__((address_space(3))) void* las3;
#define GLOAD16(gsrc, ldst) \
    __builtin_amdgcn_global_load_lds((gas1)(gsrc), (las3)(ldst), 16, 0, 0)

static __device__ __forceinline__ u16 f2bf(float f) {
    __hip_bfloat16 h = __float2bfloat16(f);
    return *reinterpret_cast<u16*>(&h);
}

// ---------------------------------------------------------------------------
// Kernel 1: per-block maxabs partials
// ---------------------------------------------------------------------------
__global__ __launch_bounds__(256) void maxabs_part(const float* __restrict__ w,
                                                   float* __restrict__ partial) {
    int tid = threadIdx.x;
    float m = 0.0f;
    for (int i = blockIdx.x * 256 + tid; i < WELEM; i += 256 * 256)
        m = fmaxf(m, fabsf(w[i]));
    #pragma unroll
    for (int off = 32; off > 0; off >>= 1) m = fmaxf(m, __shfl_xor(m, off));
    __shared__ float s[4];
    if ((tid & 63) == 0) s[tid >> 6] = m;
    __syncthreads();
    if (tid == 0) partial[blockIdx.x] = fmaxf(fmaxf(s[0], s[1]), fmaxf(s[2], s[3]));
}

// ---------------------------------------------------------------------------
// Kernel 2: reduce + faithful ternary quantize + pack bf16 into PERMUTED layout
// Apack u16 index: ((cc*4 + cot)*64 + row)*288 + tap*32 + (g ^ ((row>>1)&3))*8 + e
// ---------------------------------------------------------------------------
__global__ __launch_bounds__(256) void quant_pack(const float* __restrict__ w,
                                                  const float* __restrict__ partial,
                                                  const float* __restrict__ Wn,
                                                  u16* __restrict__ Apack) {
    int tid = threadIdx.x;
    float m = partial[tid];
    #pragma unroll
    for (int off = 32; off > 0; off >>= 1) m = fmaxf(m, __shfl_xor(m, off));
    __shared__ float s[4];
    if ((tid & 63) == 0) s[tid >> 6] = m;
    __syncthreads();
    const float mx = fmaxf(fmaxf(s[0], s[1]), fmaxf(s[2], s[3]));
    const float wn = Wn[0];

    int idx = blockIdx.x * 256 + tid;          // ((co*128+ci)*9+tap)
    float nw = w[idx] / mx;
    float q  = (nw > -THRESH && nw <= THRESH) ? 0.0f : nw;
    if (q >  THRESH) q =  1.0f;
    if (q < -THRESH) q = -1.0f;
    if (q == -1.0f)  q = wn;

    int tap = idx % 9;
    int r   = idx / 9;
    int ci  = r % CIN;
    int co  = r / CIN;
    int cc  = ci >> 5, lci = ci & 31, g = lci >> 3, e = lci & 7;
    int cot = co >> 6, row = co & 63;
    int swz = g ^ ((row >> 1) & 3);
    Apack[(size_t)((cc * 4 + cot) * 64 + row) * 288 + tap * 32 + swz * 8 + e] = f2bf(q);
}

// ---------------------------------------------------------------------------
// Kernel 3: zero the borders of padded Xt
// ---------------------------------------------------------------------------
__global__ __launch_bounds__(256) void xpad_zero(u16* __restrict__ XtP) {
    const int n = blockIdx.x;
    for (int idx = threadIdx.x; idx < 3648; idx += 256) {
        int c16 = idx & 15, s = idx >> 4;
        int r, c;
        if      (s < 58)  { r = 0;           c = s; }
        else if (s < 116) { r = 57;          c = s - 58; }
        else if (s < 172) { r = s - 116 + 1; c = 0; }
        else              { r = s - 172 + 1; c = 57; }
        size_t site = (size_t)(n * PADW + r) * PADW + c;
        *(s16x8*)(XtP + site * 128 + c16 * 8) = (s16x8){0,0,0,0,0,0,0,0};
    }
}

// ---------------------------------------------------------------------------
// Kernel 4: X (NCHW f32) -> padded Xt[n][1+h][1+w][ci] bf16 via LDS transpose
// ---------------------------------------------------------------------------
__global__ __launch_bounds__(256) void x_to_bf16t(const float* __restrict__ X,
                                                  u16* __restrict__ XtP) {
    __shared__ u16 T[64 * 136];
    const int b  = blockIdx.x;
    const int n  = b / 49, pt = b - n * 49;
    const int p0 = pt * 64;
    const int tid = threadIdx.x;
    const int ci  = tid >> 1, h2 = tid & 1;

    const float* src = X + ((size_t)(n * CIN + ci)) * HWSZ + p0 + h2 * 32;
    #pragma unroll
    for (int j = 0; j < 8; ++j) {
        f32x4 v = *(const f32x4*)(src + j * 4);
        #pragma unroll
        for (int mth = 0; mth < 4; ++mth)
            T[(h2 * 32 + j * 4 + mth) * 136 + ci] = f2bf(v[mth]);
    }
    __syncthreads();
    #pragma unroll
    for (int k = 0; k < 4; ++k) {
        int idx = tid + k * 256;
        int p = idx >> 4, c8 = idx & 15;
        int gp = p0 + p;
        int h = gp / 56, w = gp - h * 56;
        size_t site = (size_t)(n * PADW + 1 + h) * PADW + 1 + w;
        *(s16x8*)(XtP + site * 128 + c8 * 8) = *(const s16x8*)&T[p * 136 + c8 * 8];
    }
}

// ---------------------------------------------------------------------------
// Kernel 5: implicit-GEMM conv — r5 structure (double-buffered LDS, one
// barrier per chunk, 1 blk/CU) + ONE-TAP REGISTER SOFTWARE PIPELINE:
// ping-pong fragment sets af[2][4]/bf[2][4], prefetch tap t+1's 8 fragments
// (8 x ds_read_b128) before tap t's 16 MFMA, so each read has ~620 cy of
// MFMA cover (>> 120 cy LDS latency). Full unroll keeps all frag indices
// compile-time (rule 20). launch_bounds(512,2) gives 256-VGPR headroom.
// ---------------------------------------------------------------------------
__global__ __launch_bounds__(512, 2) void conv_mfma(const u16* __restrict__ XtP,
                                                    const u16* __restrict__ Apack,
                                                    float* __restrict__ out) {
    __shared__ u16 Alds[2][18432];     // 2 x 36,864 B : [64 row][288 k] linear
    __shared__ u16 Xlds[2][20480];     // 2 x 40,960 B : [640 site][32 ci] linear

    const int tid  = threadIdx.x;
    const int wid  = tid >> 6;
    const int lane = tid & 63;
    const int r16  = lane & 15;
    const int g    = lane >> 4;

    // XCD swizzle: 896 blocks, 112 per XCD -> XCD x owns images 4x..4x+3
    const int bid = blockIdx.x;
    const int s   = (bid & 7) * 112 + (bid >> 3);
    const int n   = s / 28;
    const int rem = s - n * 28;
    const int by  = rem >> 2;
    const int bx  = rem & 3;
    const int co0 = bx * 64;
    const int h0  = by * 8;

    f32x4 acc[4][4];
    #pragma unroll
    for (int i = 0; i < 4; ++i)
        #pragma unroll
        for (int j = 0; j < 4; ++j) acc[i][j] = (f32x4){0.f, 0.f, 0.f, 0.f};

    // ---- B-staging source offsets (u16 units, sans cc term) ----
    const int hbase = n * PADW + h0;
    unsigned int bsrc[5];
    #pragma unroll
    for (int i = 0; i < 5; ++i) {
        int p  = i * 512 + tid;
        int pc = (p < 2320) ? p : (p - 2320);       // clamp tail to valid sites
        int site = pc >> 2, gg = pc & 3;
        int r = site / 58, c = site - r * 58;
        int g2 = gg ^ ((site >> 1) & 3);
        bsrc[i] = (unsigned)(((hbase + r) * PADW + c) * 128 + g2 * 8);
    }

    // ---- A fragment base (u16 units): XOR term invariant in mf & tap ----
    const int abase0 = r16 * 288 + ((g ^ ((r16 >> 1) & 3)) << 3);

    // ---- B per-tap offsets (u16 units): XOR term invariant in nf ----
    int otap[9];
    #pragma unroll
    for (int t = 0; t < 9; ++t) {
        int base_t = (wid + t / 3) * 58 + r16 + (t % 3);
        otap[t] = base_t * 32 + ((g ^ ((base_t >> 1) & 3)) << 3);
    }

    // ---- prologue: stage chunk 0 into buffer 0, full drain ----
    {
        const u16* asrc = Apack + (size_t)bx * 18432;
        #pragma unroll
        for (int i = 0; i < 4; ++i)
            GLOAD16(asrc + (size_t)(i * 512 + tid) * 8, &Alds[0][(i * 512 + wid * 64) * 8]);
        if (wid < 4)
            GLOAD16(asrc + (size_t)(2048 + wid * 64 + lane) * 8, &Alds[0][(2048 + wid * 64) * 8]);
        #pragma unroll
        for (int i = 0; i < 5; ++i)
            GLOAD16(XtP + (size_t)bsrc[i], &Xlds[0][(i * 512 + wid * 64) * 8]);
        asm volatile("s_waitcnt vmcnt(0)" ::: "memory");
        __builtin_amdgcn_s_barrier();
        __builtin_amdgcn_sched_barrier(0);
    }

    #pragma unroll
    for (int cc = 0; cc < 4; ++cc) {
        const int cur = cc & 1;
        const int nxt = cur ^ 1;

        // ---- issue ALL staging for chunk cc+1 first (independent of compute)
        if (cc < 3) {
            const u16* asrc_n = Apack + (size_t)((cc + 1) * 4 + bx) * 18432;
            #pragma unroll
            for (int i = 0; i < 4; ++i)
                GLOAD16(asrc_n + (size_t)(i * 512 + tid) * 8,
                        &Alds[nxt][(i * 512 + wid * 64) * 8]);
            if (wid < 4)
                GLOAD16(asrc_n + (size_t)(2048 + wid * 64 + lane) * 8,
                        &Alds[nxt][(2048 + wid * 64) * 8]);
            #pragma unroll
            for (int i = 0; i < 5; ++i)
                GLOAD16(XtP + (size_t)bsrc[i] + (cc + 1) * 32,
                        &Xlds[nxt][(i * 512 + wid * 64) * 8]);
        }

        // ---- 9-tap stream with one-tap register prefetch pipeline ----
        const u16* Ab = &Alds[cur][abase0];
        const u16* Xb = &Xlds[cur][0];

        s16x8 af[2][4], bf[2][4];
        #pragma unroll
        for (int mf = 0; mf < 4; ++mf)
            af[0][mf] = *(const s16x8*)(Ab + mf * 4608);
        #pragma unroll
        for (int nf = 0; nf < 4; ++nf)
            bf[0][nf] = *(const s16x8*)(Xb + otap[0] + nf * 512);

        #pragma unroll
        for (int t = 0; t < 9; ++t) {
            const int c  = t & 1;
            const int nx = c ^ 1;
            if (t < 8) {
                #pragma unroll
                for (int mf = 0; mf < 4; ++mf)
                    af[nx][mf] = *(const s16x8*)(Ab + mf * 4608 + (t + 1) * 32);
                #pragma unroll
                for (int nf = 0; nf < 4; ++nf)
                    bf[nx][nf] = *(const s16x8*)(Xb + otap[t + 1] + nf * 512);
            }
            __builtin_amdgcn_s_setprio(1);
            #pragma unroll
            for (int mf = 0; mf < 4; ++mf)
                #pragma unroll
                for (int nf = 0; nf < 4; ++nf)
                    acc[mf][nf] = __builtin_amdgcn_mfma_f32_16x16x32_bf16(
                        af[c][mf], bf[c][nf], acc[mf][nf], 0, 0, 0);
            __builtin_amdgcn_s_setprio(0);
        }

        // ---- chunk boundary: drain staging, one barrier, flip ----
        if (cc < 3) {
            asm volatile("s_waitcnt vmcnt(0)" ::: "memory");
            __builtin_amdgcn_s_barrier();
            __builtin_amdgcn_sched_barrier(0);
        }
    }

    // ---- store: D col = r16 (spatial), row = g*4+j (co) ----
    const int h = h0 + wid;
    float* obase = out + ((size_t)(n * COUT + co0)) * HWSZ + h * WW;
    #pragma unroll
    for (int mf = 0; mf < 4; ++mf)
        #pragma unroll
        for (int nf = 0; nf < 4; ++nf) {
            int col = nf * 16 + r16;
            if (col < WW) {
                #pragma unroll
                for (int j = 0; j < 4; ++j) {
                    int co = mf * 16 + g * 4 + j;
                    obase[(size_t)co * HWSZ + col] = acc[mf][nf][j];
                }
            }
        }
}

// ---------------------------------------------------------------------------
// Launch
// ---------------------------------------------------------------------------
extern "C" void kernel_launch(void* const* d_in, const int* in_sizes, int n_in,
                              void* d_out, int out_size, void* d_ws, size_t ws_size,
                              hipStream_t stream) {
    const float* X      = (const float*)d_in[0];
    const float* weight = (const float*)d_in[1];
    // Wp (d_in[2]) never enters the forward (faithful to source)
    const float* Wn     = (const float*)d_in[3];
    float* out = (float*)d_out;

    float* ws_partial = (float*)d_ws;                        // 256 f32
    u16*   ws_apack   = (u16*)((char*)d_ws + 4096);          // 294912 u16
    u16*   ws_xtp     = (u16*)((char*)d_ws + (1 << 20));     // 32*3364*128 u16 (~27.5 MB)

    maxabs_part<<<256, 256, 0, stream>>>(weight, ws_partial);
    quant_pack<<<WELEM / 256, 256, 0, stream>>>(weight, ws_partial, Wn, ws_apack);
    xpad_zero<<<B_, 256, 0, stream>>>(ws_xtp);
    x_to_bf16t<<<B_ * (HWSZ / 64), 256, 0, stream>>>(X, ws_xtp);

    conv_mfma<<<896, 512, 0, stream>>>(ws_xtp, ws_apack, out);
}

// Round 8
// 91.617 us; speedup vs baseline: 1.1149x; 1.0314x over previous
//
#include <hip/hip_runtime.h>
#include <hip/hip_bf16.h>

#define THRESH 0.05f
constexpr int B_   = 32;
constexpr int CIN  = 128;
constexpr int COUT = 256;
constexpr int HH   = 56;
constexpr int WW   = 56;
constexpr int HWSZ = HH * WW;            // 3136
constexpr int WELEM = COUT * CIN * 9;    // 294912
constexpr int PADW = 58;                 // padded spatial dim

typedef unsigned short u16;
typedef __attribute__((ext_vector_type(4))) float  f32x4;
typedef __attribute__((ext_vector_type(8))) short  s16x8;

typedef const __attribute__((address_space(1))) void* gas1;
typedef __attribute__((address_space(3))) void* las3;
#define GLOAD16(gsrc, ldst) \
    __builtin_amdgcn_global_load_lds((gas1)(gsrc), (las3)(ldst), 16, 0, 0)

static __device__ __forceinline__ u16 f2bf(float f) {
    __hip_bfloat16 h = __float2bfloat16(f);
    return *reinterpret_cast<u16*>(&h);
}

// ---------------------------------------------------------------------------
// Kernel 1: per-block maxabs partials
// ---------------------------------------------------------------------------
__global__ __launch_bounds__(256) void maxabs_part(const float* __restrict__ w,
                                                   float* __restrict__ partial) {
    int tid = threadIdx.x;
    float m = 0.0f;
    for (int i = blockIdx.x * 256 + tid; i < WELEM; i += 256 * 256)
        m = fmaxf(m, fabsf(w[i]));
    #pragma unroll
    for (int off = 32; off > 0; off >>= 1) m = fmaxf(m, __shfl_xor(m, off));
    __shared__ float s[4];
    if ((tid & 63) == 0) s[tid >> 6] = m;
    __syncthreads();
    if (tid == 0) partial[blockIdx.x] = fmaxf(fmaxf(s[0], s[1]), fmaxf(s[2], s[3]));
}

// ---------------------------------------------------------------------------
// Kernel 2: reduce + faithful ternary quantize + pack bf16 into PERMUTED layout
// Apack u16 index: ((cc*4 + cot)*64 + row)*288 + tap*32 + (g ^ ((row>>1)&3))*8 + e
// ---------------------------------------------------------------------------
__global__ __launch_bounds__(256) void quant_pack(const float* __restrict__ w,
                                                  const float* __restrict__ partial,
                                                  const float* __restrict__ Wn,
                                                  u16* __restrict__ Apack) {
    int tid = threadIdx.x;
    float m = partial[tid];
    #pragma unroll
    for (int off = 32; off > 0; off >>= 1) m = fmaxf(m, __shfl_xor(m, off));
    __shared__ float s[4];
    if ((tid & 63) == 0) s[tid >> 6] = m;
    __syncthreads();
    const float mx = fmaxf(fmaxf(s[0], s[1]), fmaxf(s[2], s[3]));
    const float wn = Wn[0];

    int idx = blockIdx.x * 256 + tid;          // ((co*128+ci)*9+tap)
    float nw = w[idx] / mx;
    float q  = (nw > -THRESH && nw <= THRESH) ? 0.0f : nw;
    if (q >  THRESH) q =  1.0f;
    if (q < -THRESH) q = -1.0f;
    if (q == -1.0f)  q = wn;

    int tap = idx % 9;
    int r   = idx / 9;
    int ci  = r % CIN;
    int co  = r / CIN;
    int cc  = ci >> 5, lci = ci & 31, g = lci >> 3, e = lci & 7;
    int cot = co >> 6, row = co & 63;
    int swz = g ^ ((row >> 1) & 3);
    Apack[(size_t)((cc * 4 + cot) * 64 + row) * 288 + tap * 32 + swz * 8 + e] = f2bf(q);
}

// ---------------------------------------------------------------------------
// Kernel 3: X (NCHW f32) -> padded Xt[n][1+h][1+w][ci] bf16 via LDS transpose.
// Blocks with pt==0 additionally zero the padded borders for their image.
// grid = 32*49, block = 256
// ---------------------------------------------------------------------------
__global__ __launch_bounds__(256) void x_to_bf16t(const float* __restrict__ X,
                                                  u16* __restrict__ XtP) {
    __shared__ u16 T[64 * 136];
    const int b  = blockIdx.x;
    const int n  = b / 49, pt = b - n * 49;
    const int p0 = pt * 64;
    const int tid = threadIdx.x;
    const int ci  = tid >> 1, h2 = tid & 1;

    // border zeroing (fused former xpad_zero), disjoint addresses from interior
    if (pt == 0) {
        for (int idx = tid; idx < 3648; idx += 256) {
            int c16 = idx & 15, s = idx >> 4;
            int r, c;
            if      (s < 58)  { r = 0;           c = s; }
            else if (s < 116) { r = 57;          c = s - 58; }
            else if (s < 172) { r = s - 116 + 1; c = 0; }
            else              { r = s - 172 + 1; c = 57; }
            size_t site = (size_t)(n * PADW + r) * PADW + c;
            *(s16x8*)(XtP + site * 128 + c16 * 8) = (s16x8){0,0,0,0,0,0,0,0};
        }
    }

    const float* src = X + ((size_t)(n * CIN + ci)) * HWSZ + p0 + h2 * 32;
    #pragma unroll
    for (int j = 0; j < 8; ++j) {
        f32x4 v = *(const f32x4*)(src + j * 4);
        #pragma unroll
        for (int mth = 0; mth < 4; ++mth)
            T[(h2 * 32 + j * 4 + mth) * 136 + ci] = f2bf(v[mth]);
    }
    __syncthreads();
    #pragma unroll
    for (int k = 0; k < 4; ++k) {
        int idx = tid + k * 256;
        int p = idx >> 4, c8 = idx & 15;
        int gp = p0 + p;
        int h = gp / 56, w = gp - h * 56;
        size_t site = (size_t)(n * PADW + 1 + h) * PADW + 1 + w;
        *(s16x8*)(XtP + site * 128 + c8 * 8) = *(const s16x8*)&T[p * 136 + c8 * 8];
    }
}

// ---------------------------------------------------------------------------
// Kernel 4: implicit-GEMM conv — r5 structure (double-buffered LDS, one
// barrier per chunk, 1 blk/CU) + one-tap register pipeline HELD IN PLACE by
// sched_barrier(0) fences: [reads t+1] SB [16 MFMA on t] SB. The fences stop
// hipcc sinking the prefetch (r7 failure: VGPR stayed 88); its waitcnt pass
// then emits lgkmcnt(8) before each MFMA cluster, so the LDS pipe services
// tap t+1 while the MFMA pipe runs tap t (breaks the read/MFMA convoy).
// ---------------------------------------------------------------------------
__global__ __launch_bounds__(512, 2) void conv_mfma(const u16* __restrict__ XtP,
                                                    const u16* __restrict__ Apack,
                                                    float* __restrict__ out) {
    __shared__ u16 Alds[2][18432];     // 2 x 36,864 B : [64 row][288 k] linear
    __shared__ u16 Xlds[2][20480];     // 2 x 40,960 B : [640 site][32 ci] linear

    const int tid  = threadIdx.x;
    const int wid  = tid >> 6;
    const int lane = tid & 63;
    const int r16  = lane & 15;
    const int g    = lane >> 4;

    // XCD swizzle: 896 blocks, 112 per XCD -> XCD x owns images 4x..4x+3
    const int bid = blockIdx.x;
    const int s   = (bid & 7) * 112 + (bid >> 3);
    const int n   = s / 28;
    const int rem = s - n * 28;
    const int by  = rem >> 2;
    const int bx  = rem & 3;
    const int co0 = bx * 64;
    const int h0  = by * 8;

    f32x4 acc[4][4];
    #pragma unroll
    for (int i = 0; i < 4; ++i)
        #pragma unroll
        for (int j = 0; j < 4; ++j) acc[i][j] = (f32x4){0.f, 0.f, 0.f, 0.f};

    // ---- B-staging source offsets (u16 units, sans cc term) ----
    const int hbase = n * PADW + h0;
    unsigned int bsrc[5];
    #pragma unroll
    for (int i = 0; i < 5; ++i) {
        int p  = i * 512 + tid;
        int pc = (p < 2320) ? p : (p - 2320);       // clamp tail to valid sites
        int site = pc >> 2, gg = pc & 3;
        int r = site / 58, c = site - r * 58;
        int g2 = gg ^ ((site >> 1) & 3);
        bsrc[i] = (unsigned)(((hbase + r) * PADW + c) * 128 + g2 * 8);
    }

    // ---- A fragment base (u16 units): XOR term invariant in mf & tap ----
    const int abase0 = r16 * 288 + ((g ^ ((r16 >> 1) & 3)) << 3);

    // ---- B per-tap offsets (u16 units): XOR term invariant in nf ----
    int otap[9];
    #pragma unroll
    for (int t = 0; t < 9; ++t) {
        int base_t = (wid + t / 3) * 58 + r16 + (t % 3);
        otap[t] = base_t * 32 + ((g ^ ((base_t >> 1) & 3)) << 3);
    }

    // ---- prologue: stage chunk 0 into buffer 0, full drain ----
    {
        const u16* asrc = Apack + (size_t)bx * 18432;
        #pragma unroll
        for (int i = 0; i < 4; ++i)
            GLOAD16(asrc + (size_t)(i * 512 + tid) * 8, &Alds[0][(i * 512 + wid * 64) * 8]);
        if (wid < 4)
            GLOAD16(asrc + (size_t)(2048 + wid * 64 + lane) * 8, &Alds[0][(2048 + wid * 64) * 8]);
        #pragma unroll
        for (int i = 0; i < 5; ++i)
            GLOAD16(XtP + (size_t)bsrc[i], &Xlds[0][(i * 512 + wid * 64) * 8]);
        asm volatile("s_waitcnt vmcnt(0)" ::: "memory");
        __builtin_amdgcn_s_barrier();
        __builtin_amdgcn_sched_barrier(0);
    }

    #pragma unroll
    for (int cc = 0; cc < 4; ++cc) {
        const int cur = cc & 1;
        const int nxt = cur ^ 1;

        // ---- issue ALL staging for chunk cc+1 first (independent of compute)
        if (cc < 3) {
            const u16* asrc_n = Apack + (size_t)((cc + 1) * 4 + bx) * 18432;
            #pragma unroll
            for (int i = 0; i < 4; ++i)
                GLOAD16(asrc_n + (size_t)(i * 512 + tid) * 8,
                        &Alds[nxt][(i * 512 + wid * 64) * 8]);
            if (wid < 4)
                GLOAD16(asrc_n + (size_t)(2048 + wid * 64 + lane) * 8,
                        &Alds[nxt][(2048 + wid * 64) * 8]);
            #pragma unroll
            for (int i = 0; i < 5; ++i)
                GLOAD16(XtP + (size_t)bsrc[i] + (cc + 1) * 32,
                        &Xlds[nxt][(i * 512 + wid * 64) * 8]);
        }

        // ---- 9-tap stream with fenced one-tap register pipeline ----
        const u16* Ab = &Alds[cur][abase0];
        const u16* Xb = &Xlds[cur][0];

        s16x8 af[2][4], bf[2][4];
        #pragma unroll
        for (int mf = 0; mf < 4; ++mf)
            af[0][mf] = *(const s16x8*)(Ab + mf * 4608);
        #pragma unroll
        for (int nf = 0; nf < 4; ++nf)
            bf[0][nf] = *(const s16x8*)(Xb + otap[0] + nf * 512);

        #pragma unroll
        for (int t = 0; t < 9; ++t) {
            const int c  = t & 1;
            const int nx = c ^ 1;
            if (t < 8) {
                #pragma unroll
                for (int mf = 0; mf < 4; ++mf)
                    af[nx][mf] = *(const s16x8*)(Ab + mf * 4608 + (t + 1) * 32);
                #pragma unroll
                for (int nf = 0; nf < 4; ++nf)
                    bf[nx][nf] = *(const s16x8*)(Xb + otap[t + 1] + nf * 512);
            }
            __builtin_amdgcn_sched_barrier(0);   // pin: prefetch stays above MFMAs
            __builtin_amdgcn_s_setprio(1);
            #pragma unroll
            for (int mf = 0; mf < 4; ++mf)
                #pragma unroll
                for (int nf = 0; nf < 4; ++nf)
                    acc[mf][nf] = __builtin_amdgcn_mfma_f32_16x16x32_bf16(
                        af[c][mf], bf[c][nf], acc[mf][nf], 0, 0, 0);
            __builtin_amdgcn_s_setprio(0);
            __builtin_amdgcn_sched_barrier(0);   // pin: MFMAs stay above next prefetch
        }

        // ---- chunk boundary: drain staging, one barrier, flip ----
        if (cc < 3) {
            asm volatile("s_waitcnt vmcnt(0)" ::: "memory");
            __builtin_amdgcn_s_barrier();
            __builtin_amdgcn_sched_barrier(0);
        }
    }

    // ---- store: D col = r16 (spatial), row = g*4+j (co) ----
    const int h = h0 + wid;
    float* obase = out + ((size_t)(n * COUT + co0)) * HWSZ + h * WW;
    #pragma unroll
    for (int mf = 0; mf < 4; ++mf)
        #pragma unroll
        for (int nf = 0; nf < 4; ++nf) {
            int col = nf * 16 + r16;
            if (col < WW) {
                #pragma unroll
                for (int j = 0; j < 4; ++j) {
                    int co = mf * 16 + g * 4 + j;
                    obase[(size_t)co * HWSZ + col] = acc[mf][nf][j];
                }
            }
        }
}

// ---------------------------------------------------------------------------
// Launch
// ---------------------------------------------------------------------------
extern "C" void kernel_launch(void* const* d_in, const int* in_sizes, int n_in,
                              void* d_out, int out_size, void* d_ws, size_t ws_size,
                              hipStream_t stream) {
    const float* X      = (const float*)d_in[0];
    const float* weight = (const float*)d_in[1];
    // Wp (d_in[2]) never enters the forward (faithful to source)
    const float* Wn     = (const float*)d_in[3];
    float* out = (float*)d_out;

    float* ws_partial = (float*)d_ws;                        // 256 f32
    u16*   ws_apack   = (u16*)((char*)d_ws + 4096);          // 294912 u16
    u16*   ws_xtp     = (u16*)((char*)d_ws + (1 << 20));     // 32*3364*128 u16 (~27.5 MB)

    maxabs_part<<<256, 256, 0, stream>>>(weight, ws_partial);
    quant_pack<<<WELEM / 256, 256, 0, stream>>>(weight, ws_partial, Wn, ws_apack);
    x_to_bf16t<<<B_ * (HWSZ / 64), 256, 0, stream>>>(X, ws_xtp);

    conv_mfma<<<896, 512, 0, stream>>>(ws_xtp, ws_apack, out);
}

// Round 9
// 88.084 us; speedup vs baseline: 1.1597x; 1.0401x over previous
//
#include <hip/hip_runtime.h>
#include <hip/hip_bf16.h>

#define THRESH 0.05f
constexpr int B_   = 32;
constexpr int CIN  = 128;
constexpr int COUT = 256;
constexpr int HH   = 56;
constexpr int WW   = 56;
constexpr int HWSZ = HH * WW;            // 3136
constexpr int WELEM = COUT * CIN * 9;    // 294912
constexpr int PADW = 58;                 // padded spatial dim

typedef unsigned short u16;
typedef __attribute__((ext_vector_type(4))) float  f32x4;
typedef __attribute__((ext_vector_type(8))) short  s16x8;
typedef __attribute__((ext_vector_type(4))) int    i32x4;

typedef const __attribute__((address_space(1))) void* gas1;
typedef __attribute__((address_space(3))) void* las3;
typedef const __attribute__((address_space(3))) void* lcv;
#define GLOAD16(gsrc, ldst) \
    __builtin_amdgcn_global_load_lds((gas1)(gsrc), (las3)(ldst), 16, 0, 0)

// opaque LDS vector read: compiler cannot sink/fold/remat (r7/r8 failure fix)
#define DSR(dst, base, byteoff) \
    asm volatile("ds_read_b128 %0, %1 offset:%2" : "=v"(dst) : "v"(base), "i"(byteoff))

static __device__ __forceinline__ u16 f2bf(float f) {
    __hip_bfloat16 h = __float2bfloat16(f);
    return *reinterpret_cast<u16*>(&h);
}
static __device__ __forceinline__ s16x8 as_h(i32x4 v) {
    s16x8 r; __builtin_memcpy(&r, &v, 16); return r;
}

// ---------------------------------------------------------------------------
// Kernel 1: per-block maxabs partials
// ---------------------------------------------------------------------------
__global__ __launch_bounds__(256) void maxabs_part(const float* __restrict__ w,
                                                   float* __restrict__ partial) {
    int tid = threadIdx.x;
    float m = 0.0f;
    for (int i = blockIdx.x * 256 + tid; i < WELEM; i += 256 * 256)
        m = fmaxf(m, fabsf(w[i]));
    #pragma unroll
    for (int off = 32; off > 0; off >>= 1) m = fmaxf(m, __shfl_xor(m, off));
    __shared__ float s[4];
    if ((tid & 63) == 0) s[tid >> 6] = m;
    __syncthreads();
    if (tid == 0) partial[blockIdx.x] = fmaxf(fmaxf(s[0], s[1]), fmaxf(s[2], s[3]));
}

// ---------------------------------------------------------------------------
// Kernel 2: reduce + faithful ternary quantize + pack bf16 into PERMUTED layout
// Apack u16 index: ((cc*4 + cot)*64 + row)*288 + tap*32 + (g ^ ((row>>1)&3))*8 + e
// ---------------------------------------------------------------------------
__global__ __launch_bounds__(256) void quant_pack(const float* __restrict__ w,
                                                  const float* __restrict__ partial,
                                                  const float* __restrict__ Wn,
                                                  u16* __restrict__ Apack) {
    int tid = threadIdx.x;
    float m = partial[tid];
    #pragma unroll
    for (int off = 32; off > 0; off >>= 1) m = fmaxf(m, __shfl_xor(m, off));
    __shared__ float s[4];
    if ((tid & 63) == 0) s[tid >> 6] = m;
    __syncthreads();
    const float mx = fmaxf(fmaxf(s[0], s[1]), fmaxf(s[2], s[3]));
    const float wn = Wn[0];

    int idx = blockIdx.x * 256 + tid;          // ((co*128+ci)*9+tap)
    float nw = w[idx] / mx;
    float q  = (nw > -THRESH && nw <= THRESH) ? 0.0f : nw;
    if (q >  THRESH) q =  1.0f;
    if (q < -THRESH) q = -1.0f;
    if (q == -1.0f)  q = wn;

    int tap = idx % 9;
    int r   = idx / 9;
    int ci  = r % CIN;
    int co  = r / CIN;
    int cc  = ci >> 5, lci = ci & 31, g = lci >> 3, e = lci & 7;
    int cot = co >> 6, row = co & 63;
    int swz = g ^ ((row >> 1) & 3);
    Apack[(size_t)((cc * 4 + cot) * 64 + row) * 288 + tap * 32 + swz * 8 + e] = f2bf(q);
}

// ---------------------------------------------------------------------------
// Kernel 3: X (NCHW f32) -> padded Xt[n][1+h][1+w][ci] bf16 via LDS transpose.
// Blocks with pt==0 additionally zero the padded borders for their image.
// ---------------------------------------------------------------------------
__global__ __launch_bounds__(256) void x_to_bf16t(const float* __restrict__ X,
                                                  u16* __restrict__ XtP) {
    __shared__ u16 T[64 * 136];
    const int b  = blockIdx.x;
    const int n  = b / 49, pt = b - n * 49;
    const int p0 = pt * 64;
    const int tid = threadIdx.x;
    const int ci  = tid >> 1, h2 = tid & 1;

    if (pt == 0) {
        for (int idx = tid; idx < 3648; idx += 256) {
            int c16 = idx & 15, s = idx >> 4;
            int r, c;
            if      (s < 58)  { r = 0;           c = s; }
            else if (s < 116) { r = 57;          c = s - 58; }
            else if (s < 172) { r = s - 116 + 1; c = 0; }
            else              { r = s - 172 + 1; c = 57; }
            size_t site = (size_t)(n * PADW + r) * PADW + c;
            *(s16x8*)(XtP + site * 128 + c16 * 8) = (s16x8){0,0,0,0,0,0,0,0};
        }
    }

    const float* src = X + ((size_t)(n * CIN + ci)) * HWSZ + p0 + h2 * 32;
    #pragma unroll
    for (int j = 0; j < 8; ++j) {
        f32x4 v = *(const f32x4*)(src + j * 4);
        #pragma unroll
        for (int mth = 0; mth < 4; ++mth)
            T[(h2 * 32 + j * 4 + mth) * 136 + ci] = f2bf(v[mth]);
    }
    __syncthreads();
    #pragma unroll
    for (int k = 0; k < 4; ++k) {
        int idx = tid + k * 256;
        int p = idx >> 4, c8 = idx & 15;
        int gp = p0 + p;
        int h = gp / 56, w = gp - h * 56;
        size_t site = (size_t)(n * PADW + 1 + h) * PADW + 1 + w;
        *(s16x8*)(XtP + site * 128 + c8 * 8) = *(const s16x8*)&T[p * 136 + c8 * 8];
    }
}

// ---------------------------------------------------------------------------
// Kernel 4: implicit-GEMM conv — r5 structure + INLINE-ASM ds_read pipeline.
// Per tap: [asm ds_read x8 for tap t+1] -> s_waitcnt lgkmcnt(8) (waits only
// tap t's reads; this tap's 8 stay in flight) -> sched_barrier(0) -> 16 MFMA.
// The asm reads are opaque: hipcc cannot sink them (r7/r8 failure mode).
// ---------------------------------------------------------------------------
__global__ __launch_bounds__(512, 2) void conv_mfma(const u16* __restrict__ XtP,
                                                    const u16* __restrict__ Apack,
                                                    float* __restrict__ out) {
    __shared__ u16 Alds[2][18432];     // 2 x 36,864 B : [64 row][288 k] linear
    __shared__ u16 Xlds[2][20480];     // 2 x 40,960 B : [640 site][32 ci] linear

    const int tid  = threadIdx.x;
    const int wid  = tid >> 6;
    const int lane = tid & 63;
    const int r16  = lane & 15;
    const int g    = lane >> 4;

    // XCD swizzle: 896 blocks, 112 per XCD -> XCD x owns images 4x..4x+3
    const int bid = blockIdx.x;
    const int s   = (bid & 7) * 112 + (bid >> 3);
    const int n   = s / 28;
    const int rem = s - n * 28;
    const int by  = rem >> 2;
    const int bx  = rem & 3;
    const int co0 = bx * 64;
    const int h0  = by * 8;

    f32x4 acc[4][4];
    #pragma unroll
    for (int i = 0; i < 4; ++i)
        #pragma unroll
        for (int j = 0; j < 4; ++j) acc[i][j] = (f32x4){0.f, 0.f, 0.f, 0.f};

    // ---- B-staging source offsets (u16 units, sans cc term) ----
    const int hbase = n * PADW + h0;
    unsigned int bsrc[5];
    #pragma unroll
    for (int i = 0; i < 5; ++i) {
        int p  = i * 512 + tid;
        int pc = (p < 2320) ? p : (p - 2320);       // clamp tail to valid sites
        int site = pc >> 2, gg = pc & 3;
        int r = site / 58, c = site - r * 58;
        int g2 = gg ^ ((site >> 1) & 3);
        bsrc[i] = (unsigned)(((hbase + r) * PADW + c) * 128 + g2 * 8);
    }

    // ---- A fragment base (BYTES): XOR term invariant in mf & tap ----
    const int abase0B = (r16 * 288 + ((g ^ ((r16 >> 1) & 3)) << 3)) * 2;

    // ---- B per-tap offsets (BYTES): XOR term invariant in nf ----
    int otapB[9];
    #pragma unroll
    for (int t = 0; t < 9; ++t) {
        int base_t = (wid + t / 3) * 58 + r16 + (t % 3);
        otapB[t] = (base_t * 32 + ((g ^ ((base_t >> 1) & 3)) << 3)) * 2;
    }

    // ---- prologue: stage chunk 0 into buffer 0, full drain ----
    {
        const u16* asrc = Apack + (size_t)bx * 18432;
        #pragma unroll
        for (int i = 0; i < 4; ++i)
            GLOAD16(asrc + (size_t)(i * 512 + tid) * 8, &Alds[0][(i * 512 + wid * 64) * 8]);
        if (wid < 4)
            GLOAD16(asrc + (size_t)(2048 + wid * 64 + lane) * 8, &Alds[0][(2048 + wid * 64) * 8]);
        #pragma unroll
        for (int i = 0; i < 5; ++i)
            GLOAD16(XtP + (size_t)bsrc[i], &Xlds[0][(i * 512 + wid * 64) * 8]);
        asm volatile("s_waitcnt vmcnt(0)" ::: "memory");
        __builtin_amdgcn_s_barrier();
        __builtin_amdgcn_sched_barrier(0);
    }

    #pragma unroll
    for (int cc = 0; cc < 4; ++cc) {
        const int cur = cc & 1;
        const int nxt = cur ^ 1;

        // ---- issue ALL staging for chunk cc+1 (vmem pipe, independent) ----
        if (cc < 3) {
            const u16* asrc_n = Apack + (size_t)((cc + 1) * 4 + bx) * 18432;
            #pragma unroll
            for (int i = 0; i < 4; ++i)
                GLOAD16(asrc_n + (size_t)(i * 512 + tid) * 8,
                        &Alds[nxt][(i * 512 + wid * 64) * 8]);
            if (wid < 4)
                GLOAD16(asrc_n + (size_t)(2048 + wid * 64 + lane) * 8,
                        &Alds[nxt][(2048 + wid * 64) * 8]);
            #pragma unroll
            for (int i = 0; i < 5; ++i)
                GLOAD16(XtP + (size_t)bsrc[i] + (cc + 1) * 32,
                        &Xlds[nxt][(i * 512 + wid * 64) * 8]);
        }

        // ---- asm ds_read pipelined 9-tap stream ----
        lcv Ab = (lcv)((const char*)&Alds[cur][0] + abase0B);
        const char* XbG = (const char*)&Xlds[cur][0];

        i32x4 af[2][4], bf[2][4];
        {   // preload tap 0
            lcv xb = (lcv)(XbG + otapB[0]);
            DSR(af[0][0], Ab, 0 * 9216);
            DSR(af[0][1], Ab, 1 * 9216);
            DSR(af[0][2], Ab, 2 * 9216);
            DSR(af[0][3], Ab, 3 * 9216);
            DSR(bf[0][0], xb, 0);
            DSR(bf[0][1], xb, 1024);
            DSR(bf[0][2], xb, 2048);
            DSR(bf[0][3], xb, 3072);
        }

        #pragma unroll
        for (int t = 0; t < 9; ++t) {
            const int c  = t & 1;
            const int nx = c ^ 1;
            if (t < 8) {
                lcv xb = (lcv)(XbG + otapB[t + 1]);
                DSR(af[nx][0], Ab, 0 * 9216 + (t + 1) * 64);
                DSR(af[nx][1], Ab, 1 * 9216 + (t + 1) * 64);
                DSR(af[nx][2], Ab, 2 * 9216 + (t + 1) * 64);
                DSR(af[nx][3], Ab, 3 * 9216 + (t + 1) * 64);
                DSR(bf[nx][0], xb, 0);
                DSR(bf[nx][1], xb, 1024);
                DSR(bf[nx][2], xb, 2048);
                DSR(bf[nx][3], xb, 3072);
                asm volatile("s_waitcnt lgkmcnt(8)" ::: "memory");
            } else {
                asm volatile("s_waitcnt lgkmcnt(0)" ::: "memory");
            }
            __builtin_amdgcn_sched_barrier(0);   // rule 18: MFMAs stay below wait
            __builtin_amdgcn_s_setprio(1);
            #pragma unroll
            for (int mf = 0; mf < 4; ++mf)
                #pragma unroll
                for (int nf = 0; nf < 4; ++nf)
                    acc[mf][nf] = __builtin_amdgcn_mfma_f32_16x16x32_bf16(
                        as_h(af[c][mf]), as_h(bf[c][nf]), acc[mf][nf], 0, 0, 0);
            __builtin_amdgcn_s_setprio(0);
            __builtin_amdgcn_sched_barrier(0);   // keep next prefetch below MFMAs
        }

        // ---- chunk boundary: drain staging, one barrier, flip ----
        if (cc < 3) {
            asm volatile("s_waitcnt vmcnt(0)" ::: "memory");
            __builtin_amdgcn_s_barrier();
            __builtin_amdgcn_sched_barrier(0);
        }
    }

    // ---- store: D col = r16 (spatial), row = g*4+j (co) ----
    const int h = h0 + wid;
    float* obase = out + ((size_t)(n * COUT + co0)) * HWSZ + h * WW;
    #pragma unroll
    for (int mf = 0; mf < 4; ++mf)
        #pragma unroll
        for (int nf = 0; nf < 4; ++nf) {
            int col = nf * 16 + r16;
            if (col < WW) {
                #pragma unroll
                for (int j = 0; j < 4; ++j) {
                    int co = mf * 16 + g * 4 + j;
                    obase[(size_t)co * HWSZ + col] = acc[mf][nf][j];
                }
            }
        }
}

// ---------------------------------------------------------------------------
// Launch
// ---------------------------------------------------------------------------
extern "C" void kernel_launch(void* const* d_in, const int* in_sizes, int n_in,
                              void* d_out, int out_size, void* d_ws, size_t ws_size,
                              hipStream_t stream) {
    const float* X      = (const float*)d_in[0];
    const float* weight = (const float*)d_in[1];
    // Wp (d_in[2]) never enters the forward (faithful to source)
    const float* Wn     = (const float*)d_in[3];
    float* out = (float*)d_out;

    float* ws_partial = (float*)d_ws;                        // 256 f32
    u16*   ws_apack   = (u16*)((char*)d_ws + 4096);          // 294912 u16
    u16*   ws_xtp     = (u16*)((char*)d_ws + (1 << 20));     // 32*3364*128 u16 (~27.5 MB)

    maxabs_part<<<256, 256, 0, stream>>>(weight, ws_partial);
    quant_pack<<<WELEM / 256, 256, 0, stream>>>(weight, ws_partial, Wn, ws_apack);
    x_to_bf16t<<<B_ * (HWSZ / 64), 256, 0, stream>>>(X, ws_xtp);

    conv_mfma<<<896, 512, 0, stream>>>(ws_xtp, ws_apack, out);
}